// Round 8
// baseline (326.852 us; speedup 1.0000x reference)
//
#include <hip/hip_runtime.h>
#include <hip/hip_bf16.h>
#include <stdint.h>

// Problem constants
#define BB 4
#define LL 4096
#define DD 1024
#define HH 16
#define WW 128
#define DH 64
#define NWIN 32            // LL / WW
#define MTOT (BB*LL)       // 16384
#define NQKV (3*DD)        // 3072

typedef short bf16x8 __attribute__((ext_vector_type(8)));
typedef float f32x4 __attribute__((ext_vector_type(4)));
typedef unsigned short u16;

__device__ __forceinline__ u16 f2bf(float f) {
    union { float f; uint32_t u; } v; v.f = f;
    uint32_t u = v.u;
    uint32_t r = (u + 0x7fffu + ((u >> 16) & 1u)) >> 16;
    return (u16)r;
}

// async global->LDS, 16 bytes per lane, HW dest = wave-uniform base + lane*16
#define GLOAD_LDS16(gptr, ldsptr)                                                        \
    __builtin_amdgcn_global_load_lds((const __attribute__((address_space(1))) void*)(gptr), \
                                     (__attribute__((address_space(3))) void*)(ldsptr),      \
                                     16, 0, 0)

// ---------------- fp32 -> bf16 conversion (vectorized) ----------------
__global__ __launch_bounds__(256) void cvt_f32_bf16(const float* __restrict__ in,
                                                    u16* __restrict__ out, int n8) {
    int i = blockIdx.x * blockDim.x + threadIdx.x;
    int stride = gridDim.x * blockDim.x;
    for (; i < n8; i += stride) {
        const float4* p = (const float4*)(in + (size_t)i * 8);
        float4 a = p[0], b = p[1];
        bf16x8 o;
        o[0] = (short)f2bf(a.x); o[1] = (short)f2bf(a.y);
        o[2] = (short)f2bf(a.z); o[3] = (short)f2bf(a.w);
        o[4] = (short)f2bf(b.x); o[5] = (short)f2bf(b.y);
        o[6] = (short)f2bf(b.z); o[7] = (short)f2bf(b.w);
        *(bf16x8*)(out + (size_t)i * 8) = o;
    }
}

// =====================================================================
// 128x128-tile GEMM core, BK=32, K=1024, 256 threads = 4 waves (2M x 2N),
// per-wave 64x64 output (acc[4][4] = 64 regs -> 3 waves/SIMD target).
// LDS: 3 slots x 16 KB (A[128][32] | B[128][32], both XOR-swizzled) =
// 48 KB -> 3 blocks/CU. Blocks are NOT barrier-synced with each other:
// inter-block wave overlap hides ds/vmem latency (m114 mechanism).
//
// Pipeline: depth-2 prefetch over 3 slots. During tile j (slot j%3) we
// stage tile j+2 into slot (j+2)%3 (its last reader, tile j-1, finished
// before tile j-1's end barrier). Counted vmcnt BEFORE the tile-end
// barrier: at end of tile j, outstanding = {j-1 batch (tile j+1), j batch
// (tile j+2)} = 8 -> VM4 drains tile j+1's data, and the barrier
// propagates every wave's drain guarantee to all waves (race-free).
//
// LDS tile layout (XOR-swizzled; verified 0 conflicts in R4-R6): logical
// (row R in 0..127, 16B-slot g in 0..3) at physical R*64 + ((g ^
// ((R>>1)&3))<<4). Fragment rows wm*64+m*16+colb -> swizzle idx =
// kgrp ^ ((colb>>1)&3) (m/wm-independent, strides stay +1024).
// gload_lds dest linear; SOURCE carries inverse: thread t covers row
// t>>2 (+64 for hi half), k-elems ((t&3)^((t>>3)&3))*8.
// =====================================================================

#define VM4 asm volatile("s_waitcnt vmcnt(4)" ::: "memory")
#define VM0 asm volatile("s_waitcnt vmcnt(0)" ::: "memory")
#define VMNONE

// One K-tile: optional stage of tile sj into slot (S+2)%3, 8 ds_reads,
// 16 MFMA, counted-vm drain, barrier.
#define KTILE(S, sj, STG, VMEND, BAR) do {                                                      \
    char* sb = lds + (S)*16384;                                                                 \
    char* db = lds + (((S)+2)%3)*16384;                                                         \
    if (STG) {                                                                                  \
        GLOAD_LDS16(asrc0 + (size_t)(sj)*32, db + wave*1024);                                   \
        GLOAD_LDS16(asrc1 + (size_t)(sj)*32, db + 4096 + wave*1024);                            \
        GLOAD_LDS16(bsrc0 + (size_t)(sj)*32, db + 8192 + wave*1024);                            \
        GLOAD_LDS16(bsrc1 + (size_t)(sj)*32, db + 12288 + wave*1024);                           \
    }                                                                                           \
    bf16x8 a0 = *(const bf16x8*)(sb + aoff);                                                    \
    bf16x8 a1 = *(const bf16x8*)(sb + aoff + 1024);                                             \
    bf16x8 a2 = *(const bf16x8*)(sb + aoff + 2048);                                             \
    bf16x8 a3 = *(const bf16x8*)(sb + aoff + 3072);                                             \
    bf16x8 b0 = *(const bf16x8*)(sb + boff);                                                    \
    bf16x8 b1 = *(const bf16x8*)(sb + boff + 1024);                                             \
    bf16x8 b2 = *(const bf16x8*)(sb + boff + 2048);                                             \
    bf16x8 b3 = *(const bf16x8*)(sb + boff + 3072);                                             \
    acc[0][0] = __builtin_amdgcn_mfma_f32_16x16x32_bf16(a0, b0, acc[0][0], 0,0,0);              \
    acc[1][0] = __builtin_amdgcn_mfma_f32_16x16x32_bf16(a1, b0, acc[1][0], 0,0,0);              \
    acc[2][0] = __builtin_amdgcn_mfma_f32_16x16x32_bf16(a2, b0, acc[2][0], 0,0,0);              \
    acc[3][0] = __builtin_amdgcn_mfma_f32_16x16x32_bf16(a3, b0, acc[3][0], 0,0,0);              \
    acc[0][1] = __builtin_amdgcn_mfma_f32_16x16x32_bf16(a0, b1, acc[0][1], 0,0,0);              \
    acc[1][1] = __builtin_amdgcn_mfma_f32_16x16x32_bf16(a1, b1, acc[1][1], 0,0,0);              \
    acc[2][1] = __builtin_amdgcn_mfma_f32_16x16x32_bf16(a2, b1, acc[2][1], 0,0,0);              \
    acc[3][1] = __builtin_amdgcn_mfma_f32_16x16x32_bf16(a3, b1, acc[3][1], 0,0,0);              \
    acc[0][2] = __builtin_amdgcn_mfma_f32_16x16x32_bf16(a0, b2, acc[0][2], 0,0,0);              \
    acc[1][2] = __builtin_amdgcn_mfma_f32_16x16x32_bf16(a1, b2, acc[1][2], 0,0,0);              \
    acc[2][2] = __builtin_amdgcn_mfma_f32_16x16x32_bf16(a2, b2, acc[2][2], 0,0,0);              \
    acc[3][2] = __builtin_amdgcn_mfma_f32_16x16x32_bf16(a3, b2, acc[3][2], 0,0,0);              \
    acc[0][3] = __builtin_amdgcn_mfma_f32_16x16x32_bf16(a0, b3, acc[0][3], 0,0,0);              \
    acc[1][3] = __builtin_amdgcn_mfma_f32_16x16x32_bf16(a1, b3, acc[1][3], 0,0,0);              \
    acc[2][3] = __builtin_amdgcn_mfma_f32_16x16x32_bf16(a2, b3, acc[2][3], 0,0,0);              \
    acc[3][3] = __builtin_amdgcn_mfma_f32_16x16x32_bf16(a3, b3, acc[3][3], 0,0,0);              \
    VMEND;                                                                                      \
    if (BAR) __builtin_amdgcn_s_barrier();                                                      \
} while (0)

// Bijective XCD-chunked block swizzle; col-major (by fast -> shared B panel).
__device__ __forceinline__ void map_block(int& bx, int& by) {
    int nwg = gridDim.x;             // multiple of 8
    int wg  = blockIdx.x;
    int chunk = nwg >> 3;
    int sw = (wg & 7) * chunk + (wg >> 3);
    by = sw & 127;                   // 128 M-tiles
    bx = sw >> 7;
}

// Core: computes acc[4][4] for this block/wave. A:[M][1024], Bw:[N][1024] bf16.
__device__ __forceinline__ void gemm128_core(const u16* __restrict__ A,
                                             const u16* __restrict__ Bw,
                                             int row0, int col0,
                                             char* lds, f32x4 acc[4][4]) {
    const int tid  = threadIdx.x;
    const int lane = tid & 63;
    const int wave = tid >> 6;           // 0..3
    const int wm   = wave >> 1;          // 0..1
    const int wn   = wave & 1;           // 0..1
    const int colb = lane & 15;
    const int kgrp = lane >> 4;          // 0..3

    // fragment-read byte offsets within a slot (XOR-swizzled layout)
    const int swz  = (kgrp ^ ((colb >> 1) & 3)) << 4;
    const int aoff = (wm * 64 + colb) * 64 + swz;
    const int boff = 8192 + (wn * 64 + colb) * 64 + swz;

    // stage source mapping (inverse swizzle), per thread: 4 loads/tile
    const int lrow  = tid >> 2;                               // 0..63
    const int lkoff = ((tid & 3) ^ ((tid >> 3) & 3)) * 8;     // swizzled k-elems
    const u16* asrc0 = A  + (size_t)(row0 + lrow) * 1024 + lkoff;
    const u16* asrc1 = A  + (size_t)(row0 + 64 + lrow) * 1024 + lkoff;
    const u16* bsrc0 = Bw + (size_t)(col0 + lrow) * 1024 + lkoff;
    const u16* bsrc1 = Bw + (size_t)(col0 + 64 + lrow) * 1024 + lkoff;

    #pragma unroll
    for (int m = 0; m < 4; ++m)
        #pragma unroll
        for (int n = 0; n < 4; ++n)
            acc[m][n] = (f32x4){0.f, 0.f, 0.f, 0.f};

    // ---- prologue: stage tiles 0,1 into slots 0,1 (8 loads/thread) ----
    #pragma unroll
    for (int jj = 0; jj < 2; ++jj) {
        GLOAD_LDS16(asrc0 + jj * 32, lds + jj * 16384 + wave * 1024);
        GLOAD_LDS16(asrc1 + jj * 32, lds + jj * 16384 + 4096 + wave * 1024);
        GLOAD_LDS16(bsrc0 + jj * 32, lds + jj * 16384 + 8192 + wave * 1024);
        GLOAD_LDS16(bsrc1 + jj * 32, lds + jj * 16384 + 12288 + wave * 1024);
    }
    VM4;                                   // tile 0 drained (tile 1 in flight)
    __builtin_amdgcn_s_barrier();          // propagate drain guarantee

    // ---- main loop: tiles 0..29 (stage j+2 = 2..31) ----
    for (int jb = 0; jb < 30; jb += 3) {
        KTILE(0, jb + 2, 1, VM4, 1);
        KTILE(1, jb + 3, 1, VM4, 1);
        KTILE(2, jb + 4, 1, VM4, 1);
    }
    // ---- tail: tiles 30, 31 ----
    KTILE(0, 0, 0, VM0, 1);                // tile 30; drain tile-31 batch
    KTILE(1, 0, 0, VMNONE, 0);             // tile 31
}

// ---------------- Kernel 1: QKV GEMM + bias + scatter to windowed q/k/vT ----------------
__global__ __launch_bounds__(256, 3) void qkv_gemm_kernel(const u16* __restrict__ xb,
                                                          const u16* __restrict__ wb,
                                                          const float* __restrict__ bias,
                                                          u16* __restrict__ qd,
                                                          u16* __restrict__ kd,
                                                          u16* __restrict__ vtd) {
    __shared__ char g_lds[49152];
    f32x4 acc[4][4];
    int bx, by;
    map_block(bx, by);
    const int row0 = by * 128;
    const int col0 = bx * 128;
    gemm128_core(xb, wb, row0, col0, g_lds, acc);

    const int lane = threadIdx.x & 63;
    const int wave = threadIdx.x >> 6;
    const int wm = wave >> 1, wn = wave & 1;
    const int colb = lane & 15;
    const int rgrp = lane >> 4;

    #pragma unroll
    for (int m = 0; m < 4; ++m) {
        #pragma unroll
        for (int n = 0; n < 4; ++n) {
            #pragma unroll
            for (int j = 0; j < 4; ++j) {
                int gm = row0 + wm * 64 + m * 16 + rgrp * 4 + j;
                int gn = col0 + wn * 64 + n * 16 + colb;
                float v = acc[m][n][j] + bias[gn];
                int which = gn >> 10, c = gn & 1023, h = c >> 6, d = c & 63;
                int b = gm >> 12, l = gm & 4095, n0 = l >> 7, wq = l & 127;
                size_t wbase = (size_t)((b * HH + h) * NWIN + n0) * (WW * DH);
                if (which == 0)      qd [wbase + wq * 64 + d] = f2bf(v * 0.125f);
                else if (which == 1) kd [wbase + wq * 64 + d] = f2bf(v);
                else                 vtd[wbase + d * 128 + wq] = f2bf(v);
            }
        }
    }
}

// ---------------- Kernel 3: output projection GEMM + bias -> fp32 out ----------------
__global__ __launch_bounds__(256, 3) void out_gemm_kernel(const u16* __restrict__ ab,
                                                          const u16* __restrict__ wb,
                                                          const float* __restrict__ bias,
                                                          float* __restrict__ out) {
    __shared__ char g_lds[49152];
    f32x4 acc[4][4];
    int bx, by;
    map_block(bx, by);
    const int row0 = by * 128;
    const int col0 = bx * 128;
    gemm128_core(ab, wb, row0, col0, g_lds, acc);

    const int lane = threadIdx.x & 63;
    const int wave = threadIdx.x >> 6;
    const int wm = wave >> 1, wn = wave & 1;
    const int colb = lane & 15;
    const int rgrp = lane >> 4;

    #pragma unroll
    for (int m = 0; m < 4; ++m) {
        #pragma unroll
        for (int n = 0; n < 4; ++n) {
            #pragma unroll
            for (int j = 0; j < 4; ++j) {
                int gm = row0 + wm * 64 + m * 16 + rgrp * 4 + j;
                int gn = col0 + wn * 64 + n * 16 + colb;
                out[(size_t)gm * DD + gn] = acc[m][n][j] + bias[gn];
            }
        }
    }
}

// ---------------- Kernel 2: windowed causal attention (unchanged) ----------------
__global__ __launch_bounds__(256) void attn_kernel(const u16* __restrict__ q,
                                                   const u16* __restrict__ k,
                                                   const u16* __restrict__ vt,
                                                   u16* __restrict__ aout) {
    __shared__ u16 Ps[4][32 * 136];   // per-wave P tile, padded rows

    const int win = blockIdx.x;          // 0..2047
    const int b  = win >> 9;
    const int h  = (win >> 5) & 15;
    const int n0 = win & 31;
    const u16* qp = q  + (size_t)win * (WW * DH);
    const u16* kp = k  + (size_t)win * (WW * DH);
    const u16* vp = vt + (size_t)win * (WW * DH);

    const int lane = threadIdx.x & 63;
    const int wave = threadIdx.x >> 6;
    const int wrow = wave * 32;
    const int colb = lane & 15;
    const int kgrp = lane >> 4;
    const int rgrp = kgrp;

    f32x4 s[2][8];
    #pragma unroll
    for (int m = 0; m < 2; ++m)
        #pragma unroll
        for (int n = 0; n < 8; ++n)
            s[m][n] = (f32x4){0.f, 0.f, 0.f, 0.f};

    #pragma unroll
    for (int kk = 0; kk < 2; ++kk) {
        bf16x8 aq[2];
        #pragma unroll
        for (int m = 0; m < 2; ++m)
            aq[m] = *(const bf16x8*)&qp[(wrow + m * 16 + colb) * 64 + kk * 32 + kgrp * 8];
        #pragma unroll
        for (int n = 0; n < 8; ++n) {
            bf16x8 bk = *(const bf16x8*)&kp[(n * 16 + colb) * 64 + kk * 32 + kgrp * 8];
            s[0][n] = __builtin_amdgcn_mfma_f32_16x16x32_bf16(aq[0], bk, s[0][n], 0, 0, 0);
            s[1][n] = __builtin_amdgcn_mfma_f32_16x16x32_bf16(aq[1], bk, s[1][n], 0, 0, 0);
        }
    }

    #pragma unroll
    for (int m = 0; m < 2; ++m) {
        #pragma unroll
        for (int j = 0; j < 4; ++j) {
            int row = wrow + m * 16 + rgrp * 4 + j;
            float vals[8];
            float mx = -1e30f;
            #pragma unroll
            for (int n = 0; n < 8; ++n) {
                int col = n * 16 + colb;
                float v = s[m][n][j];
                if (col > row) v = -1e30f;
                vals[n] = v;
                mx = fmaxf(mx, v);
            }
            #pragma unroll
            for (int off = 1; off < 16; off <<= 1)
                mx = fmaxf(mx, __shfl_xor(mx, off, 64));
            float sum = 0.f;
            #pragma unroll
            for (int n = 0; n < 8; ++n) {
                float p = __expf(vals[n] - mx);
                vals[n] = p;
                sum += p;
            }
            #pragma unroll
            for (int off = 1; off < 16; off <<= 1)
                sum += __shfl_xor(sum, off, 64);
            float r = 1.0f / sum;
            #pragma unroll
            for (int n = 0; n < 8; ++n)
                Ps[wave][(m * 16 + rgrp * 4 + j) * 136 + n * 16 + colb] = f2bf(vals[n] * r);
        }
    }
    __syncthreads();

    f32x4 o[2][4];
    #pragma unroll
    for (int m = 0; m < 2; ++m)
        #pragma unroll
        for (int n = 0; n < 4; ++n)
            o[m][n] = (f32x4){0.f, 0.f, 0.f, 0.f};

    #pragma unroll
    for (int kk = 0; kk < 4; ++kk) {
        bf16x8 ap[2];
        #pragma unroll
        for (int m = 0; m < 2; ++m)
            ap[m] = *(const bf16x8*)&Ps[wave][(m * 16 + colb) * 136 + kk * 32 + kgrp * 8];
        #pragma unroll
        for (int n = 0; n < 4; ++n) {
            bf16x8 bv = *(const bf16x8*)&vp[(n * 16 + colb) * 128 + kk * 32 + kgrp * 8];
            o[0][n] = __builtin_amdgcn_mfma_f32_16x16x32_bf16(ap[0], bv, o[0][n], 0, 0, 0);
            o[1][n] = __builtin_amdgcn_mfma_f32_16x16x32_bf16(ap[1], bv, o[1][n], 0, 0, 0);
        }
    }

    #pragma unroll
    for (int m = 0; m < 2; ++m) {
        #pragma unroll
        for (int n = 0; n < 4; ++n) {
            #pragma unroll
            for (int j = 0; j < 4; ++j) {
                int row = wrow + m * 16 + rgrp * 4 + j;
                int l = n0 * 128 + row;
                int d = h * 64 + n * 16 + colb;
                aout[((size_t)(b * LL + l)) * DD + d] = f2bf(o[m][n][j]);
            }
        }
    }
}

// ---------------- launch ----------------
extern "C" void kernel_launch(void* const* d_in, const int* in_sizes, int n_in,
                              void* d_out, int out_size, void* d_ws, size_t ws_size,
                              hipStream_t stream) {
    const float* x     = (const float*)d_in[0];
    const float* qkv_w = (const float*)d_in[1];
    const float* qkv_b = (const float*)d_in[2];
    const float* out_w = (const float*)d_in[3];
    const float* out_b = (const float*)d_in[4];
    float* out = (float*)d_out;

    char* ws = (char*)d_ws;
    u16* xb   = (u16*)(ws);                           // 16,777,216 elems (reused as attn_out)
    u16* qwb  = (u16*)(ws + 33554432);                // 3,145,728 elems
    u16* owb  = (u16*)(ws + 39845888);                // 1,048,576 elems
    u16* qws  = (u16*)(ws + 41943040);
    u16* kws  = (u16*)(ws + 75497472);
    u16* vtws = (u16*)(ws + 109051904);

    cvt_f32_bf16<<<2048, 256, 0, stream>>>(x, xb, 16777216 / 8);
    cvt_f32_bf16<<<1536, 256, 0, stream>>>(qkv_w, qwb, 3145728 / 8);
    cvt_f32_bf16<<<512, 256, 0, stream>>>(out_w, owb, 1048576 / 8);

    qkv_gemm_kernel<<<(MTOT / 128) * (NQKV / 128), 256, 0, stream>>>(xb, qwb, qkv_b, qws, kws, vtws);

    attn_kernel<<<BB * HH * NWIN, 256, 0, stream>>>(qws, kws, vtws, xb /* attn_out */);

    out_gemm_kernel<<<(MTOT / 128) * (DD / 128), 256, 0, stream>>>(xb, owb, out_b, out);
}

// Round 9
// 296.065 us; speedup vs baseline: 1.1040x; 1.1040x over previous
//
#include <hip/hip_runtime.h>
#include <hip/hip_bf16.h>
#include <stdint.h>

// Problem constants
#define BB 4
#define LL 4096
#define DD 1024
#define HH 16
#define WW 128
#define DH 64
#define NWIN 32            // LL / WW
#define MTOT (BB*LL)       // 16384
#define NQKV (3*DD)        // 3072

typedef short bf16x8 __attribute__((ext_vector_type(8)));
typedef float f32x4 __attribute__((ext_vector_type(4)));
typedef unsigned short u16;

__device__ __forceinline__ u16 f2bf(float f) {
    union { float f; uint32_t u; } v; v.f = f;
    uint32_t u = v.u;
    uint32_t r = (u + 0x7fffu + ((u >> 16) & 1u)) >> 16;
    return (u16)r;
}

// async global->LDS, 16 bytes per lane, HW dest = wave-uniform base + lane*16
#define GLOAD_LDS16(gptr, ldsptr)                                                        \
    __builtin_amdgcn_global_load_lds((const __attribute__((address_space(1))) void*)(gptr), \
                                     (__attribute__((address_space(3))) void*)(ldsptr),      \
                                     16, 0, 0)

// ---------------- fp32 -> bf16 conversion (vectorized) ----------------
__global__ __launch_bounds__(256) void cvt_f32_bf16(const float* __restrict__ in,
                                                    u16* __restrict__ out, int n8) {
    int i = blockIdx.x * blockDim.x + threadIdx.x;
    int stride = gridDim.x * blockDim.x;
    for (; i < n8; i += stride) {
        const float4* p = (const float4*)(in + (size_t)i * 8);
        float4 a = p[0], b = p[1];
        bf16x8 o;
        o[0] = (short)f2bf(a.x); o[1] = (short)f2bf(a.y);
        o[2] = (short)f2bf(a.z); o[3] = (short)f2bf(a.w);
        o[4] = (short)f2bf(b.x); o[5] = (short)f2bf(b.y);
        o[6] = (short)f2bf(b.z); o[7] = (short)f2bf(b.w);
        *(bf16x8*)(out + (size_t)i * 8) = o;
    }
}

// =====================================================================
// 256x256 tile, BK=64, K=1024 (16 K-tiles), 512 threads = 8 waves (2Mx4N),
// wave tile 128x64, acc[8][4]. Faithful m201 8-phase port:
//   dbuf=2 x 64KB. Buffer = 2 k-slices (k0-31, k32-63); each slice is the
//   verified R4 32KB layout {A-lo,A-hi,B-lo,B-hi}[128r][32k], XOR-swizzled
//   (0 bank conflicts, verified R4-R6).
//   4 phases per K-tile; each phase: {4-8 ds_read_b128, 2 gload_lds} ->
//   barrier -> lgkmcnt(0) -> sched_barrier -> setprio(1) -> 16 MFMA ->
//   setprio(0) -> [vmcnt(4) at p1,p3] -> barrier.
//   COLLECTIVE vmcnt: counted vmcnt immediately before a barrier forces
//   every thread's 4-oldest stages landed, and the barrier publishes the
//   guarantee -> k-slice data provably lands one slice ahead of its reads
//   (steady state: at p3-end, outstanding = next tile's 8 units, vmcnt(4)
//   forces its s0; at p1-end, forces its s1). Tail uses vmcnt(0) at p1.
// =====================================================================

#define RD(p)  (*(const bf16x8*)(p))
#define BARR   __builtin_amdgcn_s_barrier()
#define LGKM0  asm volatile("s_waitcnt lgkmcnt(0)" ::: "memory")
#define SCB    __builtin_amdgcn_sched_barrier(0)
#define PRIO1  __builtin_amdgcn_s_setprio(1)
#define PRIO0  __builtin_amdgcn_s_setprio(0)
#define VM4    asm volatile("s_waitcnt vmcnt(4)" ::: "memory")
#define VM0    asm volatile("s_waitcnt vmcnt(0)" ::: "memory")
#define VMNONE

#define PHASE_MFMA(MB)                                                                      \
    acc[(MB)+0][0] = __builtin_amdgcn_mfma_f32_16x16x32_bf16(a0, b0, acc[(MB)+0][0], 0,0,0); \
    acc[(MB)+1][0] = __builtin_amdgcn_mfma_f32_16x16x32_bf16(a1, b0, acc[(MB)+1][0], 0,0,0); \
    acc[(MB)+2][0] = __builtin_amdgcn_mfma_f32_16x16x32_bf16(a2, b0, acc[(MB)+2][0], 0,0,0); \
    acc[(MB)+3][0] = __builtin_amdgcn_mfma_f32_16x16x32_bf16(a3, b0, acc[(MB)+3][0], 0,0,0); \
    acc[(MB)+0][1] = __builtin_amdgcn_mfma_f32_16x16x32_bf16(a0, b1, acc[(MB)+0][1], 0,0,0); \
    acc[(MB)+1][1] = __builtin_amdgcn_mfma_f32_16x16x32_bf16(a1, b1, acc[(MB)+1][1], 0,0,0); \
    acc[(MB)+2][1] = __builtin_amdgcn_mfma_f32_16x16x32_bf16(a2, b1, acc[(MB)+2][1], 0,0,0); \
    acc[(MB)+3][1] = __builtin_amdgcn_mfma_f32_16x16x32_bf16(a3, b1, acc[(MB)+3][1], 0,0,0); \
    acc[(MB)+0][2] = __builtin_amdgcn_mfma_f32_16x16x32_bf16(a0, b2, acc[(MB)+0][2], 0,0,0); \
    acc[(MB)+1][2] = __builtin_amdgcn_mfma_f32_16x16x32_bf16(a1, b2, acc[(MB)+1][2], 0,0,0); \
    acc[(MB)+2][2] = __builtin_amdgcn_mfma_f32_16x16x32_bf16(a2, b2, acc[(MB)+2][2], 0,0,0); \
    acc[(MB)+3][2] = __builtin_amdgcn_mfma_f32_16x16x32_bf16(a3, b2, acc[(MB)+3][2], 0,0,0); \
    acc[(MB)+0][3] = __builtin_amdgcn_mfma_f32_16x16x32_bf16(a0, b3, acc[(MB)+0][3], 0,0,0); \
    acc[(MB)+1][3] = __builtin_amdgcn_mfma_f32_16x16x32_bf16(a1, b3, acc[(MB)+1][3], 0,0,0); \
    acc[(MB)+2][3] = __builtin_amdgcn_mfma_f32_16x16x32_bf16(a2, b3, acc[(MB)+2][3], 0,0,0); \
    acc[(MB)+3][3] = __builtin_amdgcn_mfma_f32_16x16x32_bf16(a3, b3, acc[(MB)+3][3], 0,0,0);

// One BK=64 K-tile = 4 phases. B = buffer (0/1), sj = K-tile being staged
// into buffer B^1, STG = stage?, VMP1/VMP3 = counted vmcnt before the
// p1/p3 end barriers.
#define KTILE64(B, sj, STG, VMP1, VMP3) do {                                                \
    char* s0 = lds + (B)*65536;                                                             \
    char* s1 = s0 + 32768;                                                                  \
    char* db = lds + ((B)^1)*65536;                                                         \
    bf16x8 a0, a1, a2, a3, b0, b1, b2, b3;                                                  \
    /* p0: reads A[m0-3]s0 + B s0 (8); stage A-lo,A-hi s0 of tile sj */                     \
    a0 = RD(s0 + aoff);        a1 = RD(s0 + aoff + 1024);                                   \
    a2 = RD(s0 + aoff + 2048); a3 = RD(s0 + aoff + 3072);                                   \
    b0 = RD(s0 + boff);        b1 = RD(s0 + boff + 1024);                                   \
    b2 = RD(s0 + boff + 2048); b3 = RD(s0 + boff + 3072);                                   \
    if (STG) {                                                                              \
        GLOAD_LDS16(asrcL + (size_t)(sj)*64, db + wave*1024);                               \
        GLOAD_LDS16(asrcH + (size_t)(sj)*64, db + 8192 + wave*1024);                        \
    }                                                                                       \
    BARR; LGKM0; SCB; PRIO1; PHASE_MFMA(0) PRIO0; BARR;                                     \
    /* p1: reads A[m4-7]s0 (4, B reused); stage B-lo,B-hi s0 */                             \
    a0 = RD(s0 + aoff + 4096); a1 = RD(s0 + aoff + 5120);                                   \
    a2 = RD(s0 + aoff + 6144); a3 = RD(s0 + aoff + 7168);                                   \
    if (STG) {                                                                              \
        GLOAD_LDS16(bsrcL + (size_t)(sj)*64, db + 16384 + wave*1024);                       \
        GLOAD_LDS16(bsrcH + (size_t)(sj)*64, db + 24576 + wave*1024);                       \
    }                                                                                       \
    BARR; LGKM0; SCB; PRIO1; PHASE_MFMA(4) PRIO0; VMP1; BARR;                               \
    /* p2: reads A[m0-3]s1 + B s1 (8); stage A s1 */                                        \
    a0 = RD(s1 + aoff);        a1 = RD(s1 + aoff + 1024);                                   \
    a2 = RD(s1 + aoff + 2048); a3 = RD(s1 + aoff + 3072);                                   \
    b0 = RD(s1 + boff);        b1 = RD(s1 + boff + 1024);                                   \
    b2 = RD(s1 + boff + 2048); b3 = RD(s1 + boff + 3072);                                   \
    if (STG) {                                                                              \
        GLOAD_LDS16(asrcL + (size_t)(sj)*64 + 32, db + 32768 + wave*1024);                  \
        GLOAD_LDS16(asrcH + (size_t)(sj)*64 + 32, db + 32768 + 8192 + wave*1024);           \
    }                                                                                       \
    BARR; LGKM0; SCB; PRIO1; PHASE_MFMA(0) PRIO0; BARR;                                     \
    /* p3: reads A[m4-7]s1 (4); stage B s1 */                                               \
    a0 = RD(s1 + aoff + 4096); a1 = RD(s1 + aoff + 5120);                                   \
    a2 = RD(s1 + aoff + 6144); a3 = RD(s1 + aoff + 7168);                                   \
    if (STG) {                                                                              \
        GLOAD_LDS16(bsrcL + (size_t)(sj)*64 + 32, db + 32768 + 16384 + wave*1024);          \
        GLOAD_LDS16(bsrcH + (size_t)(sj)*64 + 32, db + 32768 + 24576 + wave*1024);          \
    }                                                                                       \
    BARR; LGKM0; SCB; PRIO1; PHASE_MFMA(4) PRIO0; VMP3; BARR;                               \
} while (0)

// Bijective XCD-chunked block swizzle; col-major (by fast -> shared B panel).
__device__ __forceinline__ void map_block(int& bx, int& by) {
    int nwg = gridDim.x;             // multiple of 8
    int wg  = blockIdx.x;
    int chunk = nwg >> 3;
    int sw = (wg & 7) * chunk + (wg >> 3);
    by = sw & 63;                    // 64 M-tiles
    bx = sw >> 6;
}

// Core: computes acc[8][4] for this block/wave. A:[M][1024], Bw:[N][1024] bf16.
__device__ __forceinline__ void gemm256_core(const u16* __restrict__ A,
                                             const u16* __restrict__ Bw,
                                             int row0, int col0,
                                             char* lds, f32x4 acc[8][4]) {
    const int tid  = threadIdx.x;
    const int lane = tid & 63;
    const int wave = tid >> 6;
    const int wm   = wave >> 2;          // 0..1
    const int wn   = wave & 3;           // 0..3
    const int colb = lane & 15;
    const int kgrp = lane >> 4;          // 0..3

    // fragment-read byte offsets within a 32KB k-slice (XOR-swizzled layout)
    const int swz  = (kgrp ^ ((colb >> 1) & 3)) << 4;
    const int aoff = wm * 8192 + colb * 64 + swz;
    const int boff = 16384 + (wn >> 1) * 8192 + (wn & 1) * 4096 + colb * 64 + swz;

    // stage source mapping (inverse swizzle), per thread: 1 load per 8KB unit
    const int lrow  = tid >> 2;                               // 0..127
    const int lkoff = ((tid & 3) ^ ((tid >> 3) & 3)) * 8;     // swizzled k-elems
    const u16* asrcL = A  + (size_t)(row0 + lrow) * 1024 + lkoff;
    const u16* asrcH = A  + (size_t)(row0 + 128 + lrow) * 1024 + lkoff;
    const u16* bsrcL = Bw + (size_t)(col0 + lrow) * 1024 + lkoff;
    const u16* bsrcH = Bw + (size_t)(col0 + 128 + lrow) * 1024 + lkoff;

    #pragma unroll
    for (int m = 0; m < 8; ++m)
        #pragma unroll
        for (int n = 0; n < 4; ++n)
            acc[m][n] = (f32x4){0.f, 0.f, 0.f, 0.f};

    // ---- prologue: stage K-tile 0 (8 units) into buf0; force s0 landed ----
    GLOAD_LDS16(asrcL,      lds + wave*1024);
    GLOAD_LDS16(asrcH,      lds + 8192 + wave*1024);
    GLOAD_LDS16(bsrcL,      lds + 16384 + wave*1024);
    GLOAD_LDS16(bsrcH,      lds + 24576 + wave*1024);
    GLOAD_LDS16(asrcL + 32, lds + 32768 + wave*1024);
    GLOAD_LDS16(asrcH + 32, lds + 32768 + 8192 + wave*1024);
    GLOAD_LDS16(bsrcL + 32, lds + 32768 + 16384 + wave*1024);
    GLOAD_LDS16(bsrcH + 32, lds + 32768 + 24576 + wave*1024);
    VM4;                           // s0 of tile 0 landed (collective via barrier)
    BARR;

    // ---- main loop: 16 K-tiles; tile j reads buf j&1, stages j+1 ----
    for (int jj = 0; jj < 14; jj += 2) {
        KTILE64(0, jj + 1, 1, VM4, VM4);
        KTILE64(1, jj + 2, 1, VM4, VM4);
    }
    KTILE64(0, 15, 1, VM4, VM4);           // j=14, stages tile 15 -> buf1
    KTILE64(1, 0, 0, VM0, VMNONE);         // j=15 tail (VM0 at p1 forces s1)
}

// ---------------- Kernel 1: QKV GEMM + bias + scatter to windowed q/k/vT ----------------
__global__ __launch_bounds__(512, 2) void qkv_gemm_kernel(const u16* __restrict__ xb,
                                                          const u16* __restrict__ wb,
                                                          const float* __restrict__ bias,
                                                          u16* __restrict__ qd,
                                                          u16* __restrict__ kd,
                                                          u16* __restrict__ vtd) {
    __shared__ char g_lds[131072];
    f32x4 acc[8][4];
    int bx, by;
    map_block(bx, by);
    const int row0 = by * 256;
    const int col0 = bx * 256;
    gemm256_core(xb, wb, row0, col0, g_lds, acc);

    const int lane = threadIdx.x & 63;
    const int wave = threadIdx.x >> 6;
    const int wm = wave >> 2, wn = wave & 3;
    const int colb = lane & 15;
    const int rgrp = lane >> 4;

    #pragma unroll
    for (int m = 0; m < 8; ++m) {
        #pragma unroll
        for (int n = 0; n < 4; ++n) {
            #pragma unroll
            for (int j = 0; j < 4; ++j) {
                int gm = row0 + wm * 128 + m * 16 + rgrp * 4 + j;
                int gn = col0 + wn * 64 + n * 16 + colb;
                float v = acc[m][n][j] + bias[gn];
                int which = gn >> 10, c = gn & 1023, h = c >> 6, d = c & 63;
                int b = gm >> 12, l = gm & 4095, n0 = l >> 7, wq = l & 127;
                size_t wbase = (size_t)((b * HH + h) * NWIN + n0) * (WW * DH);
                if (which == 0)      qd [wbase + wq * 64 + d] = f2bf(v * 0.125f);
                else if (which == 1) kd [wbase + wq * 64 + d] = f2bf(v);
                else                 vtd[wbase + d * 128 + wq] = f2bf(v);
            }
        }
    }
}

// ---------------- Kernel 3: output projection GEMM + bias -> fp32 out ----------------
__global__ __launch_bounds__(512, 2) void out_gemm_kernel(const u16* __restrict__ ab,
                                                          const u16* __restrict__ wb,
                                                          const float* __restrict__ bias,
                                                          float* __restrict__ out) {
    __shared__ char g_lds[131072];
    f32x4 acc[8][4];
    int bx, by;
    map_block(bx, by);
    const int row0 = by * 256;
    const int col0 = bx * 256;
    gemm256_core(ab, wb, row0, col0, g_lds, acc);

    const int lane = threadIdx.x & 63;
    const int wave = threadIdx.x >> 6;
    const int wm = wave >> 2, wn = wave & 3;
    const int colb = lane & 15;
    const int rgrp = lane >> 4;

    #pragma unroll
    for (int m = 0; m < 8; ++m) {
        #pragma unroll
        for (int n = 0; n < 4; ++n) {
            #pragma unroll
            for (int j = 0; j < 4; ++j) {
                int gm = row0 + wm * 128 + m * 16 + rgrp * 4 + j;
                int gn = col0 + wn * 64 + n * 16 + colb;
                out[(size_t)gm * DD + gn] = acc[m][n][j] + bias[gn];
            }
        }
    }
}

// ---------------- Kernel 2: windowed causal attention (unchanged) ----------------
__global__ __launch_bounds__(256) void attn_kernel(const u16* __restrict__ q,
                                                   const u16* __restrict__ k,
                                                   const u16* __restrict__ vt,
                                                   u16* __restrict__ aout) {
    __shared__ u16 Ps[4][32 * 136];   // per-wave P tile, padded rows

    const int win = blockIdx.x;          // 0..2047
    const int b  = win >> 9;
    const int h  = (win >> 5) & 15;
    const int n0 = win & 31;
    const u16* qp = q  + (size_t)win * (WW * DH);
    const u16* kp = k  + (size_t)win * (WW * DH);
    const u16* vp = vt + (size_t)win * (WW * DH);

    const int lane = threadIdx.x & 63;
    const int wave = threadIdx.x >> 6;
    const int wrow = wave * 32;
    const int colb = lane & 15;
    const int kgrp = lane >> 4;
    const int rgrp = kgrp;

    f32x4 s[2][8];
    #pragma unroll
    for (int m = 0; m < 2; ++m)
        #pragma unroll
        for (int n = 0; n < 8; ++n)
            s[m][n] = (f32x4){0.f, 0.f, 0.f, 0.f};

    #pragma unroll
    for (int kk = 0; kk < 2; ++kk) {
        bf16x8 aq[2];
        #pragma unroll
        for (int m = 0; m < 2; ++m)
            aq[m] = *(const bf16x8*)&qp[(wrow + m * 16 + colb) * 64 + kk * 32 + kgrp * 8];
        #pragma unroll
        for (int n = 0; n < 8; ++n) {
            bf16x8 bk = *(const bf16x8*)&kp[(n * 16 + colb) * 64 + kk * 32 + kgrp * 8];
            s[0][n] = __builtin_amdgcn_mfma_f32_16x16x32_bf16(aq[0], bk, s[0][n], 0, 0, 0);
            s[1][n] = __builtin_amdgcn_mfma_f32_16x16x32_bf16(aq[1], bk, s[1][n], 0, 0, 0);
        }
    }

    #pragma unroll
    for (int m = 0; m < 2; ++m) {
        #pragma unroll
        for (int j = 0; j < 4; ++j) {
            int row = wrow + m * 16 + rgrp * 4 + j;
            float vals[8];
            float mx = -1e30f;
            #pragma unroll
            for (int n = 0; n < 8; ++n) {
                int col = n * 16 + colb;
                float v = s[m][n][j];
                if (col > row) v = -1e30f;
                vals[n] = v;
                mx = fmaxf(mx, v);
            }
            #pragma unroll
            for (int off = 1; off < 16; off <<= 1)
                mx = fmaxf(mx, __shfl_xor(mx, off, 64));
            float sum = 0.f;
            #pragma unroll
            for (int n = 0; n < 8; ++n) {
                float p = __expf(vals[n] - mx);
                vals[n] = p;
                sum += p;
            }
            #pragma unroll
            for (int off = 1; off < 16; off <<= 1)
                sum += __shfl_xor(sum, off, 64);
            float r = 1.0f / sum;
            #pragma unroll
            for (int n = 0; n < 8; ++n)
                Ps[wave][(m * 16 + rgrp * 4 + j) * 136 + n * 16 + colb] = f2bf(vals[n] * r);
        }
    }
    __syncthreads();

    f32x4 o[2][4];
    #pragma unroll
    for (int m = 0; m < 2; ++m)
        #pragma unroll
        for (int n = 0; n < 4; ++n)
            o[m][n] = (f32x4){0.f, 0.f, 0.f, 0.f};

    #pragma unroll
    for (int kk = 0; kk < 4; ++kk) {
        bf16x8 ap[2];
        #pragma unroll
        for (int m = 0; m < 2; ++m)
            ap[m] = *(const bf16x8*)&Ps[wave][(m * 16 + colb) * 136 + kk * 32 + kgrp * 8];
        #pragma unroll
        for (int n = 0; n < 4; ++n) {
            bf16x8 bv = *(const bf16x8*)&vp[(n * 16 + colb) * 128 + kk * 32 + kgrp * 8];
            o[0][n] = __builtin_amdgcn_mfma_f32_16x16x32_bf16(ap[0], bv, o[0][n], 0, 0, 0);
            o[1][n] = __builtin_amdgcn_mfma_f32_16x16x32_bf16(ap[1], bv, o[1][n], 0, 0, 0);
        }
    }

    #pragma unroll
    for (int m = 0; m < 2; ++m) {
        #pragma unroll
        for (int n = 0; n < 4; ++n) {
            #pragma unroll
            for (int j = 0; j < 4; ++j) {
                int row = wrow + m * 16 + rgrp * 4 + j;
                int l = n0 * 128 + row;
                int d = h * 64 + n * 16 + colb;
                aout[((size_t)(b * LL + l)) * DD + d] = f2bf(o[m][n][j]);
            }
        }
    }
}

// ---------------- launch ----------------
extern "C" void kernel_launch(void* const* d_in, const int* in_sizes, int n_in,
                              void* d_out, int out_size, void* d_ws, size_t ws_size,
                              hipStream_t stream) {
    const float* x     = (const float*)d_in[0];
    const float* qkv_w = (const float*)d_in[1];
    const float* qkv_b = (const float*)d_in[2];
    const float* out_w = (const float*)d_in[3];
    const float* out_b = (const float*)d_in[4];
    float* out = (float*)d_out;

    char* ws = (char*)d_ws;
    u16* xb   = (u16*)(ws);                           // 16,777,216 elems (reused as attn_out)
    u16* qwb  = (u16*)(ws + 33554432);                // 3,145,728 elems
    u16* owb  = (u16*)(ws + 39845888);                // 1,048,576 elems
    u16* qws  = (u16*)(ws + 41943040);
    u16* kws  = (u16*)(ws + 75497472);
    u16* vtws = (u16*)(ws + 109051904);

    cvt_f32_bf16<<<2048, 256, 0, stream>>>(x, xb, 16777216 / 8);
    cvt_f32_bf16<<<1536, 256, 0, stream>>>(qkv_w, qwb, 3145728 / 8);
    cvt_f32_bf16<<<512, 256, 0, stream>>>(out_w, owb, 1048576 / 8);

    qkv_gemm_kernel<<<(MTOT / 256) * (NQKV / 256), 512, 0, stream>>>(xb, qwb, qkv_b, qws, kws, vtws);

    attn_kernel<<<BB * HH * NWIN, 256, 0, stream>>>(qws, kws, vtws, xb /* attn_out */);

    out_gemm_kernel<<<(MTOT / 256) * (DD / 256), 512, 0, stream>>>(xb, owb, out_b, out);
}